// Round 1
// baseline (291.988 us; speedup 1.0000x reference)
//
#include <hip/hip_runtime.h>
#include <stdint.h>

// Problem constants (match reference)
#define HH 512
#define WW 512
#define CC 3
#define KK 32
#define SS 4
#define PP 10
#define NPATCH 126            // (512 + 20 - 32)/4 + 1
#define NP2 (NPATCH * NPATCH) // 15876
#define DD 3072               // C*K*K
#define NMEM 4096
#define THRESHV 0.5f

// ws layout (uint32 words):
// [0] nfail counter
// [1] min ||m||^2 bits (positive float -> uint bit order == float order)
// [2] max ||m||^2 bits
// [3] mapped max of folded output (monotonic uint mapping, handles negatives)
// [4..] failing-patch index list

__device__ inline float wave_reduce_sum(float v) {
    for (int off = 32; off; off >>= 1) v += __shfl_xor(v, off, 64);
    return v;
}

__device__ inline uint32_t map_f(float f) {
    uint32_t b = __float_as_uint(f);
    return (b & 0x80000000u) ? ~b : (b | 0x80000000u);
}

__global__ void init_ws(uint32_t* ws) {
    if (threadIdx.x == 0) {
        ws[0] = 0u;
        ws[1] = 0x7F800000u; // +inf
        ws[2] = 0u;          // 0.0f
        ws[3] = 0u;          // minimum of the monotonic mapping
    }
}

// One wave per mem row: ||m_j||^2, then global min/max via uint atomics.
__global__ void mem_norms(const float* __restrict__ mem, uint32_t* ws) {
    int row  = (blockIdx.x * blockDim.x + threadIdx.x) >> 6;
    int lane = threadIdx.x & 63;
    if (row >= NMEM) return;
    const float* r = mem + (size_t)row * DD;
    float s = 0.f;
    for (int d = lane; d < DD; d += 64) { float v = r[d]; s += v * v; }
    s = wave_reduce_sum(s);
    if (lane == 0) {
        atomicMin(&ws[1], __float_as_uint(s));
        atomicMax(&ws[2], __float_as_uint(s));
    }
}

// One wave per patch: ||u_i||^2 from the (virtually padded) image, then the
// reverse-triangle-inequality bound check:  d2 >= (||m|| - ||u||)^2.
// Patches whose bound cannot certify dmin >= THRESH are queued for the exact
// fallback pass.
__global__ void patch_check(const float* __restrict__ img, uint32_t* ws,
                            uint32_t cap) {
    int patch = (blockIdx.x * blockDim.x + threadIdx.x) >> 6;
    int lane  = threadIdx.x & 63;
    if (patch >= NP2) return;
    int pi = patch / NPATCH, pj = patch % NPATCH;
    int y0 = pi * SS - PP, x0 = pj * SS - PP;
    int kx = lane & 31, ky0 = lane >> 5;
    float s = 0.f;
    int x = x0 + kx;
    if (x >= 0 && x < WW) {
        for (int ky = ky0; ky < KK; ky += 2) {
            int y = y0 + ky;
            if (y < 0 || y >= HH) continue;
            const float* p = img + ((size_t)y * WW + x) * CC;
            float a = p[0], b = p[1], c = p[2];
            s += a * a + b * b + c * c;
        }
    }
    s = wave_reduce_sum(s);
    if (lane == 0) {
        float un = sqrtf(s);
        float mn = sqrtf(__uint_as_float(ws[1]));
        float mx = sqrtf(__uint_as_float(ws[2]));
        float gap = 0.f;
        if (un <= mn) gap = mn - un;
        else if (un >= mx) gap = un - mx;
        // else gap = 0 -> cannot certify, goes to fallback
        if (gap * gap < THRESHV) {
            uint32_t idx = atomicAdd(&ws[0], 1u);
            if (idx < cap) ws[4 + idx] = (uint32_t)patch;
        }
    }
}

// Coverage count along one axis: # of patch positions i with i*S <= v+P <= i*S+K-1
__device__ inline int cov1(int v) {
    int pv = v + PP;
    int a = pv - (KK - 1);
    int imin = (a <= 0) ? 0 : ((a + SS - 1) >> 2);
    int imax = pv >> 2;
    if (imax > NPATCH - 1) imax = NPATCH - 1;
    return imax - imin + 1;
}

// Certified path: fold(unfold(img)) == img * cov(y) * cov(x)  (exact gather form)
__global__ void fold_main(const float* __restrict__ img, float* __restrict__ out) {
    int t = blockIdx.x * blockDim.x + threadIdx.x; // over H*W pixels
    if (t >= HH * WW) return;
    int y = t / WW, x = t - y * WW;
    float c = (float)(cov1(y) * cov1(x));
    const float* p = img + (size_t)t * CC;
    float* o = out + (size_t)t * CC;
    o[0] = p[0] * c;
    o[1] = p[1] * c;
    o[2] = p[2] * c;
}

// Exact fallback for patches the bound couldn't certify (normally zero work):
// compute the full distance row, argmin (first-index tie-break), and if
// dmin < THRESH atomically swap this patch's contribution u -> recon.
__global__ void fallback_fix(const float* __restrict__ img,
                             const float* __restrict__ mem,
                             const float* __restrict__ mem2,
                             const int* __restrict__ mapping,
                             uint32_t* ws, float* out, uint32_t cap) {
    __shared__ float smin[256];
    __shared__ int   sarg[256];
    uint32_t nfail = ws[0];
    if (nfail > cap) nfail = cap;
    for (uint32_t f = blockIdx.x; f < nfail; f += gridDim.x) {
        int patch = (int)ws[4 + f];
        int pi = patch / NPATCH, pj = patch % NPATCH;
        int y0 = pi * SS - PP, x0 = pj * SS - PP;
        float best = INFINITY; int barg = NMEM;
        for (int j = threadIdx.x; j < NMEM; j += blockDim.x) {
            const float* m = mem + (size_t)j * DD;
            float s = 0.f;
            for (int d = 0; d < DD; ++d) {
                int c = d >> 10, rem = d & 1023, ky = rem >> 5, kx = rem & 31;
                int y = y0 + ky, x = x0 + kx;
                float u = (y >= 0 && y < HH && x >= 0 && x < WW)
                              ? img[((size_t)y * WW + x) * CC + c] : 0.f;
                float dif = u - m[d];
                s += dif * dif;
            }
            if (s < best) { best = s; barg = j; }
        }
        smin[threadIdx.x] = best; sarg[threadIdx.x] = barg;
        __syncthreads();
        for (int stride = 128; stride; stride >>= 1) {
            if ((int)threadIdx.x < stride) {
                float s2 = smin[threadIdx.x + stride];
                int   a2 = sarg[threadIdx.x + stride];
                if (s2 < smin[threadIdx.x] ||
                    (s2 == smin[threadIdx.x] && a2 < sarg[threadIdx.x])) {
                    smin[threadIdx.x] = s2; sarg[threadIdx.x] = a2;
                }
            }
            __syncthreads();
        }
        float dmin = smin[0]; int arg = sarg[0];
        if (dmin < THRESHV) {
            const float* rec = mem2 + (size_t)mapping[arg] * DD;
            for (int d = threadIdx.x; d < DD; d += blockDim.x) {
                int c = d >> 10, rem = d & 1023, ky = rem >> 5, kx = rem & 31;
                int y = y0 + ky, x = x0 + kx;
                if (y >= 0 && y < HH && x >= 0 && x < WW) {
                    float u = img[((size_t)y * WW + x) * CC + c];
                    atomicAdd(&out[((size_t)y * WW + x) * CC + c], rec[d] - u);
                }
            }
        }
        __syncthreads();
    }
}

__global__ void max_reduce(const float* __restrict__ out, uint32_t* ws) {
    const int n = HH * WW * CC;
    float m = -INFINITY;
    for (int i = blockIdx.x * blockDim.x + threadIdx.x; i < n;
         i += gridDim.x * blockDim.x)
        m = fmaxf(m, out[i]);
    for (int off = 32; off; off >>= 1) m = fmaxf(m, __shfl_xor(m, off, 64));
    if ((threadIdx.x & 63) == 0) atomicMax(&ws[3], map_f(m));
}

__global__ void normalize_k(float* out, const uint32_t* ws) {
    uint32_t key = ws[3];
    uint32_t b = (key & 0x80000000u) ? (key & 0x7FFFFFFFu) : ~key;
    float mx = __uint_as_float(b);
    int i = blockIdx.x * blockDim.x + threadIdx.x;
    if (i < HH * WW * CC) out[i] /= mx;
}

extern "C" void kernel_launch(void* const* d_in, const int* in_sizes, int n_in,
                              void* d_out, int out_size, void* d_ws, size_t ws_size,
                              hipStream_t stream) {
    const float* img     = (const float*)d_in[0];
    const float* mem     = (const float*)d_in[1];
    const float* mem2    = (const float*)d_in[2];
    const int*   mapping = (const int*)d_in[3];
    float* out   = (float*)d_out;
    uint32_t* ws = (uint32_t*)d_ws;

    uint32_t cap = 0;
    if (ws_size >= 16) {
        size_t words = ws_size / 4;
        cap = (uint32_t)((words > 4) ? (words - 4) : 0);
        if (cap > NP2) cap = NP2;
    }

    init_ws<<<1, 64, 0, stream>>>(ws);
    mem_norms<<<(NMEM * 64) / 256, 256, 0, stream>>>(mem, ws);
    patch_check<<<(NP2 * 64 + 255) / 256, 256, 0, stream>>>(img, ws, cap);
    fold_main<<<(HH * WW + 255) / 256, 256, 0, stream>>>(img, out);
    fallback_fix<<<64, 256, 0, stream>>>(img, mem, mem2, mapping, ws, out, cap);
    max_reduce<<<1024, 256, 0, stream>>>(out, ws);
    normalize_k<<<(HH * WW * CC + 255) / 256, 256, 0, stream>>>(out, ws);
}

// Round 2
// 145.824 us; speedup vs baseline: 2.0023x; 2.0023x over previous
//
#include <hip/hip_runtime.h>
#include <stdint.h>

// Problem constants (match reference)
#define HH 512
#define WW 512
#define CC 3
#define KK 32
#define SS 4
#define PP 10
#define NPATCH 126            // (512 + 20 - 32)/4 + 1
#define NP2 (NPATCH * NPATCH) // 15876
#define DD 3072               // C*K*K
#define NMEM 4096
#define THRESHV 0.5f

// ws layout (uint32 words):
// [0] nfail counter
// [1] min ||m||^2 bits
// [2] max ||m||^2 bits
// [3] mapped max of folded output (monotonic uint mapping, handles negatives)
// [4 .. 4+NMEM)   per-row mem norm^2 (float)
// [FAIL_OFF ..]   failing-patch index list
#define FAIL_OFF (4 + NMEM)

__device__ inline float wave_reduce_sum(float v) {
    for (int off = 32; off; off >>= 1) v += __shfl_xor(v, off, 64);
    return v;
}

__device__ inline uint32_t map_f(float f) {
    uint32_t b = __float_as_uint(f);
    return (b & 0x80000000u) ? ~b : (b | 0x80000000u);
}

__global__ void init_ws(uint32_t* ws) {
    if (threadIdx.x == 0) {
        ws[0] = 0u;
        ws[1] = 0x7F800000u; // +inf (placeholder, overwritten by minmax_k)
        ws[2] = 0u;
        ws[3] = 0u;          // minimum of the monotonic max mapping
    }
}

// One wave per mem row: ||m_j||^2 via 12 fully-unrolled float4 loads
// (12 outstanding 16B loads per lane -> latency hidden). No atomics:
// result stored per-row, reduced by minmax_k.
__global__ void mem_norms(const float* __restrict__ mem,
                          float* __restrict__ norms) {
    int row  = blockIdx.x * (blockDim.x >> 6) + (threadIdx.x >> 6);
    int lane = threadIdx.x & 63;
    if (row >= NMEM) return;
    const float4* r = (const float4*)(mem + (size_t)row * DD); // 768 float4/row
    float4 v[12];
#pragma unroll
    for (int i = 0; i < 12; ++i) v[i] = r[lane + (i << 6)];
    float s0 = 0.f, s1 = 0.f, s2 = 0.f, s3 = 0.f;
#pragma unroll
    for (int i = 0; i < 12; ++i) {
        s0 += v[i].x * v[i].x; s1 += v[i].y * v[i].y;
        s2 += v[i].z * v[i].z; s3 += v[i].w * v[i].w;
    }
    float s = (s0 + s1) + (s2 + s3);
    s = wave_reduce_sum(s);
    if (lane == 0) norms[row] = s;
}

// Single block: min/max over the 4096 row norms -> ws[1], ws[2].
__global__ void minmax_k(const float* __restrict__ norms, uint32_t* ws) {
    __shared__ float smn[4], smx[4];
    float mn = INFINITY, mx = -INFINITY;
    for (int i = threadIdx.x; i < NMEM; i += 256) {
        float v = norms[i];
        mn = fminf(mn, v);
        mx = fmaxf(mx, v);
    }
    for (int off = 32; off; off >>= 1) {
        mn = fminf(mn, __shfl_xor(mn, off, 64));
        mx = fmaxf(mx, __shfl_xor(mx, off, 64));
    }
    int w = threadIdx.x >> 6;
    if ((threadIdx.x & 63) == 0) { smn[w] = mn; smx[w] = mx; }
    __syncthreads();
    if (threadIdx.x == 0) {
        mn = fminf(fminf(smn[0], smn[1]), fminf(smn[2], smn[3]));
        mx = fmaxf(fmaxf(smx[0], smx[1]), fmaxf(smx[2], smx[3]));
        ws[1] = __float_as_uint(mn);
        ws[2] = __float_as_uint(mx);
    }
}

// Separable patch-norm + reverse-triangle-inequality certification.
// Block = one patch-row py (512 threads): thread x computes the 32-row
// column window-sum of per-pixel squared norms into LDS; then the first
// 126 threads sum 32 LDS values for their patch norm and run the bound
// check:  d2 >= (||m|| - ||u||)^2.  Uncertified patches -> failure list.
__global__ void patch_rows(const float* __restrict__ img, uint32_t* ws,
                           uint32_t cap) {
    __shared__ float cs[WW];
    int py = blockIdx.x;
    int x  = threadIdx.x; // 0..511
    int y0 = py * SS - PP;
    float s = 0.f;
#pragma unroll
    for (int ky = 0; ky < KK; ++ky) {
        int y = y0 + ky;
        if (y >= 0 && y < HH) {
            const float* p = img + ((size_t)y * WW + x) * CC;
            s += p[0] * p[0] + p[1] * p[1] + p[2] * p[2];
        }
    }
    cs[x] = s;
    __syncthreads();
    if (x < NPATCH) {
        int x0 = x * SS - PP;
        float t = 0.f;
#pragma unroll
        for (int kx = 0; kx < KK; ++kx) {
            int xx = x0 + kx;
            if (xx >= 0 && xx < WW) t += cs[xx];
        }
        float un = sqrtf(t);
        float mn = sqrtf(__uint_as_float(ws[1]));
        float mx = sqrtf(__uint_as_float(ws[2]));
        float gap = 0.f;
        if (un <= mn) gap = mn - un;
        else if (un >= mx) gap = un - mx;
        // else gap = 0 -> cannot certify, exact fallback handles it
        if (gap * gap < THRESHV) {
            uint32_t idx = atomicAdd(&ws[0], 1u);
            if (idx < cap) ws[FAIL_OFF + idx] = (uint32_t)(py * NPATCH + x);
        }
    }
}

// Coverage count along one axis: # patch positions i with i*S <= v+P <= i*S+K-1
__device__ inline int cov1(int v) {
    int pv = v + PP;
    int a = pv - (KK - 1);
    int imin = (a <= 0) ? 0 : ((a + SS - 1) >> 2);
    int imax = pv >> 2;
    if (imax > NPATCH - 1) imax = NPATCH - 1;
    return imax - imin + 1;
}

// Certified path: fold(unfold(img)) == img * cov(y) * cov(x)
__global__ void fold_main(const float* __restrict__ img, float* __restrict__ out) {
    int t = blockIdx.x * blockDim.x + threadIdx.x; // over H*W pixels
    if (t >= HH * WW) return;
    int y = t / WW, x = t - y * WW;
    float c = (float)(cov1(y) * cov1(x));
    const float* p = img + (size_t)t * CC;
    float* o = out + (size_t)t * CC;
    o[0] = p[0] * c;
    o[1] = p[1] * c;
    o[2] = p[2] * c;
}

// Exact fallback for patches the bound couldn't certify (normally zero work).
__global__ void fallback_fix(const float* __restrict__ img,
                             const float* __restrict__ mem,
                             const float* __restrict__ mem2,
                             const int* __restrict__ mapping,
                             uint32_t* ws, float* out, uint32_t cap) {
    __shared__ float smin[256];
    __shared__ int   sarg[256];
    uint32_t nfail = ws[0];
    if (nfail > cap) nfail = cap;
    for (uint32_t f = blockIdx.x; f < nfail; f += gridDim.x) {
        int patch = (int)ws[FAIL_OFF + f];
        int pi = patch / NPATCH, pj = patch % NPATCH;
        int y0 = pi * SS - PP, x0 = pj * SS - PP;
        float best = INFINITY; int barg = NMEM;
        for (int j = threadIdx.x; j < NMEM; j += blockDim.x) {
            const float* m = mem + (size_t)j * DD;
            float s = 0.f;
            for (int d = 0; d < DD; ++d) {
                int c = d >> 10, rem = d & 1023, ky = rem >> 5, kx = rem & 31;
                int y = y0 + ky, x = x0 + kx;
                float u = (y >= 0 && y < HH && x >= 0 && x < WW)
                              ? img[((size_t)y * WW + x) * CC + c] : 0.f;
                float dif = u - m[d];
                s += dif * dif;
            }
            if (s < best) { best = s; barg = j; }
        }
        smin[threadIdx.x] = best; sarg[threadIdx.x] = barg;
        __syncthreads();
        for (int stride = 128; stride; stride >>= 1) {
            if ((int)threadIdx.x < stride) {
                float s2 = smin[threadIdx.x + stride];
                int   a2 = sarg[threadIdx.x + stride];
                if (s2 < smin[threadIdx.x] ||
                    (s2 == smin[threadIdx.x] && a2 < sarg[threadIdx.x])) {
                    smin[threadIdx.x] = s2; sarg[threadIdx.x] = a2;
                }
            }
            __syncthreads();
        }
        float dmin = smin[0]; int arg = sarg[0];
        if (dmin < THRESHV) {
            const float* rec = mem2 + (size_t)mapping[arg] * DD;
            for (int d = threadIdx.x; d < DD; d += blockDim.x) {
                int c = d >> 10, rem = d & 1023, ky = rem >> 5, kx = rem & 31;
                int y = y0 + ky, x = x0 + kx;
                if (y >= 0 && y < HH && x >= 0 && x < WW) {
                    float u = img[((size_t)y * WW + x) * CC + c];
                    atomicAdd(&out[((size_t)y * WW + x) * CC + c], rec[d] - u);
                }
            }
        }
        __syncthreads();
    }
}

// Global max of folded output: float4 scan, block-level LDS reduce,
// ONE atomic per block (256 total, uncontended enough).
__global__ void max_reduce(const float* __restrict__ out, uint32_t* ws) {
    __shared__ float sm[4];
    const int n4 = (HH * WW * CC) / 4; // 196608
    const float4* o4 = (const float4*)out;
    float m = -INFINITY;
    for (int i = blockIdx.x * blockDim.x + threadIdx.x; i < n4;
         i += gridDim.x * blockDim.x) {
        float4 v = o4[i];
        m = fmaxf(m, fmaxf(fmaxf(v.x, v.y), fmaxf(v.z, v.w)));
    }
    for (int off = 32; off; off >>= 1) m = fmaxf(m, __shfl_xor(m, off, 64));
    int w = threadIdx.x >> 6;
    if ((threadIdx.x & 63) == 0) sm[w] = m;
    __syncthreads();
    if (threadIdx.x == 0) {
        m = fmaxf(fmaxf(sm[0], sm[1]), fmaxf(sm[2], sm[3]));
        atomicMax(&ws[3], map_f(m));
    }
}

__global__ void normalize_k(float* out, const uint32_t* ws) {
    uint32_t key = ws[3];
    uint32_t b = (key & 0x80000000u) ? (key & 0x7FFFFFFFu) : ~key;
    float inv = 1.0f / __uint_as_float(b);
    const int n4 = (HH * WW * CC) / 4;
    int i = blockIdx.x * blockDim.x + threadIdx.x;
    if (i < n4) {
        float4* o4 = (float4*)out;
        float4 v = o4[i];
        v.x *= inv; v.y *= inv; v.z *= inv; v.w *= inv;
        o4[i] = v;
    }
}

extern "C" void kernel_launch(void* const* d_in, const int* in_sizes, int n_in,
                              void* d_out, int out_size, void* d_ws, size_t ws_size,
                              hipStream_t stream) {
    const float* img     = (const float*)d_in[0];
    const float* mem     = (const float*)d_in[1];
    const float* mem2    = (const float*)d_in[2];
    const int*   mapping = (const int*)d_in[3];
    float* out   = (float*)d_out;
    uint32_t* ws = (uint32_t*)d_ws;
    float* norms = (float*)(ws + 4);

    uint32_t cap = 0;
    size_t words = ws_size / 4;
    if (words > (size_t)FAIL_OFF) {
        cap = (uint32_t)(words - FAIL_OFF);
        if (cap > NP2) cap = NP2;
    }

    init_ws<<<1, 64, 0, stream>>>(ws);
    mem_norms<<<NMEM / 4, 256, 0, stream>>>(mem, norms);       // 4 waves/block
    minmax_k<<<1, 256, 0, stream>>>(norms, ws);
    fold_main<<<(HH * WW + 255) / 256, 256, 0, stream>>>(img, out);
    patch_rows<<<NPATCH, 512, 0, stream>>>(img, ws, cap);
    fallback_fix<<<64, 256, 0, stream>>>(img, mem, mem2, mapping, ws, out, cap);
    max_reduce<<<256, 256, 0, stream>>>(out, ws);
    normalize_k<<<(HH * WW * CC / 4 + 255) / 256, 256, 0, stream>>>(out, ws);
}

// Round 3
// 143.703 us; speedup vs baseline: 2.0319x; 1.0148x over previous
//
#include <hip/hip_runtime.h>
#include <stdint.h>

// Problem constants (match reference)
#define HH 512
#define WW 512
#define CC 3
#define KK 32
#define SS 4
#define PP 10
#define NPATCH 126            // (512 + 20 - 32)/4 + 1
#define NP2 (NPATCH * NPATCH) // 15876
#define DD 3072               // C*K*K
#define NMEM 4096
#define THRESHV 0.5f

// ws layout (32-bit words). NOTHING here needs pre-initialization: every word
// consumed is unconditionally written by an earlier kernel in the chain.
#define OFF_NORMS  0        // 4096 floats: per-row ||m||^2
#define OFF_CNT    4096     // 126 uint:   per-patch-row fail count
#define OFF_FAIL   4352     // 126*128 uint: per-row fail index list
#define OFF_PMAXA  20480    // 1024 floats: per-block max of certified fold
#define OFF_PMAXB  21504    // 1024 floats: per-block max after fallback fixes

__device__ inline float wave_max(float v) {
    for (int off = 32; off; off >>= 1) v = fmaxf(v, __shfl_xor(v, off, 64));
    return v;
}
__device__ inline float wave_min(float v) {
    for (int off = 32; off; off >>= 1) v = fminf(v, __shfl_xor(v, off, 64));
    return v;
}
__device__ inline float wave_sum(float v) {
    for (int off = 32; off; off >>= 1) v += __shfl_xor(v, off, 64);
    return v;
}
__device__ inline int wave_sum_i(int v) {
    for (int off = 32; off; off >>= 1) v += __shfl_xor(v, off, 64);
    return v;
}

// Coverage count along one axis: # patch positions i with i*S <= v+P <= i*S+K-1
__device__ inline int cov1(int v) {
    int pv = v + PP;
    int a = pv - (KK - 1);
    int imin = (a <= 0) ? 0 : ((a + SS - 1) >> 2);
    int imax = pv >> 2;
    if (imax > NPATCH - 1) imax = NPATCH - 1;
    return imax - imin + 1;
}

// Kernel A: fused mem row-norms + certified fold (out = img * cov_y * cov_x).
// grid 1024 x 256. Block b: waves 0..3 compute norms of rows 4b..4b+3 via 12
// fully-unrolled float4 loads; threads 0..191 also fold 192 float4s of the
// image and track a per-block max -> pmaxA[b]. No atomics anywhere.
__global__ void norms_fold(const float* __restrict__ mem,
                           const float* __restrict__ img,
                           float* __restrict__ norms,
                           float* __restrict__ pmaxA,
                           float* __restrict__ out) {
    __shared__ float smx[4];
    int b = blockIdx.x, tid = threadIdx.x;
    int lane = tid & 63, w = tid >> 6;

    // ---- fold part (threads 0..191; 1024*192 float4 == H*W*C/4) ----
    float m = -INFINITY;
    if (tid < 192) {
        int f = b * 192 + tid;
        float4 v = ((const float4*)img)[f];
        float r[4] = {v.x, v.y, v.z, v.w};
        int e = f * 4;
#pragma unroll
        for (int k = 0; k < 4; ++k) {
            int px = (e + k) / 3;
            int y = px >> 9, x = px & 511;
            float cv = (float)(cov1(y) * cov1(x));
            r[k] *= cv;
            m = fmaxf(m, r[k]);
        }
        float4 o; o.x = r[0]; o.y = r[1]; o.z = r[2]; o.w = r[3];
        ((float4*)out)[f] = o;
    }

    // ---- norms part (all 4 waves, one mem row each) ----
    int row = b * 4 + w;
    const float4* rp = (const float4*)(mem + (size_t)row * DD); // 768 f4/row
    float4 v[12];
#pragma unroll
    for (int i = 0; i < 12; ++i) v[i] = rp[lane + (i << 6)];
    float s0 = 0.f, s1 = 0.f, s2 = 0.f, s3 = 0.f;
#pragma unroll
    for (int i = 0; i < 12; ++i) {
        s0 += v[i].x * v[i].x; s1 += v[i].y * v[i].y;
        s2 += v[i].z * v[i].z; s3 += v[i].w * v[i].w;
    }
    float s = wave_sum((s0 + s1) + (s2 + s3));
    if (lane == 0) norms[row] = s;

    // ---- block max -> pmaxA[b] ----
    m = wave_max(m);
    if (lane == 0) smx[w] = m;
    __syncthreads();
    if (tid == 0)
        pmaxA[b] = fmaxf(fmaxf(smx[0], smx[1]), fmaxf(smx[2], smx[3]));
}

// Kernel B: per-patch-row certification. Block py (512 threads):
//  1) redundantly min/max-reduce the 4096 mem norms (L2-hot, ~1us)
//  2) column window-sums of per-pixel |.|^2 into LDS
//  3) 126 patch norms + reverse-triangle bound  d2 >= (||m||-||u||)^2
// Uncertified patches go to this row's private fail list (no global atomics).
__global__ void patch_cert(const float* __restrict__ img,
                           const float* __restrict__ norms,
                           uint32_t* __restrict__ counts,
                           uint32_t* __restrict__ fails) {
    __shared__ float cs[WW];
    __shared__ float red[16];
    __shared__ float s_mn, s_mx;
    __shared__ uint32_t s_cnt;
    __shared__ uint32_t s_list[NPATCH];
    int py = blockIdx.x;
    int tid = threadIdx.x;           // 0..511
    int lane = tid & 63, w = tid >> 6; // 8 waves

    if (tid == 0) s_cnt = 0;

    // 1) min/max of norms
    float mn = INFINITY, mx = -INFINITY;
#pragma unroll
    for (int k = 0; k < 8; ++k) {
        float v = norms[tid + (k << 9)];
        mn = fminf(mn, v); mx = fmaxf(mx, v);
    }
    mn = wave_min(mn); mx = wave_max(mx);
    if (lane == 0) { red[w] = mn; red[8 + w] = mx; }
    __syncthreads();
    if (tid == 0) {
        float a = INFINITY, bmx = -INFINITY;
#pragma unroll
        for (int k = 0; k < 8; ++k) {
            a = fminf(a, red[k]); bmx = fmaxf(bmx, red[8 + k]);
        }
        s_mn = sqrtf(a); s_mx = sqrtf(bmx);
    }

    // 2) column sums of squared pixel norms over this patch-row's 32 y-rows
    int y0 = py * SS - PP;
    float s = 0.f;
#pragma unroll
    for (int ky = 0; ky < KK; ++ky) {
        int y = y0 + ky;
        if (y >= 0 && y < HH) {
            const float* p = img + ((size_t)y * WW + tid) * CC;
            s += p[0] * p[0] + p[1] * p[1] + p[2] * p[2];
        }
    }
    cs[tid] = s;
    __syncthreads();

    // 3) patch norms + bound check
    if (tid < NPATCH) {
        int x0 = tid * SS - PP;
        float t = 0.f;
#pragma unroll
        for (int kx = 0; kx < KK; ++kx) {
            int xx = x0 + kx;
            if (xx >= 0 && xx < WW) t += cs[xx];
        }
        float un = sqrtf(t);
        float gap = 0.f;
        if (un <= s_mn) gap = s_mn - un;
        else if (un >= s_mx) gap = un - s_mx;
        if (gap * gap < THRESHV) {
            uint32_t pos = atomicAdd(&s_cnt, 1u); // LDS atomic only
            s_list[pos] = (uint32_t)(py * NPATCH + tid);
        }
    }
    __syncthreads();
    uint32_t c = s_cnt;
    if (tid == 0) counts[py] = c;
    if (tid < c) fails[py * 128 + tid] = s_list[tid];
}

// Kernel C: exact fallback for uncertified patches (normally zero work —
// reads 126 counts and exits).
__global__ void fallback_fix(const float* __restrict__ img,
                             const float* __restrict__ mem,
                             const float* __restrict__ mem2,
                             const int* __restrict__ mapping,
                             const uint32_t* __restrict__ counts,
                             const uint32_t* __restrict__ fails,
                             float* __restrict__ out) {
    __shared__ float smin[256];
    __shared__ int   sarg[256];
    int seq = 0;
    for (int py = 0; py < NPATCH; ++py) {
        uint32_t cnt = counts[py];
        for (uint32_t e = 0; e < cnt; ++e, ++seq) {
            if ((uint32_t)(seq % gridDim.x) != blockIdx.x) continue;
            int patch = (int)fails[py * 128 + e];
            int pi = patch / NPATCH, pj = patch % NPATCH;
            int y0 = pi * SS - PP, x0 = pj * SS - PP;
            float best = INFINITY; int barg = NMEM;
            for (int j = threadIdx.x; j < NMEM; j += blockDim.x) {
                const float* mr = mem + (size_t)j * DD;
                float s = 0.f;
                for (int d = 0; d < DD; ++d) {
                    int c = d >> 10, rem = d & 1023, ky = rem >> 5, kx = rem & 31;
                    int y = y0 + ky, x = x0 + kx;
                    float u = (y >= 0 && y < HH && x >= 0 && x < WW)
                                  ? img[((size_t)y * WW + x) * CC + c] : 0.f;
                    float dif = u - mr[d];
                    s += dif * dif;
                }
                if (s < best) { best = s; barg = j; }
            }
            smin[threadIdx.x] = best; sarg[threadIdx.x] = barg;
            __syncthreads();
            for (int stride = 128; stride; stride >>= 1) {
                if ((int)threadIdx.x < stride) {
                    float s2 = smin[threadIdx.x + stride];
                    int   a2 = sarg[threadIdx.x + stride];
                    if (s2 < smin[threadIdx.x] ||
                        (s2 == smin[threadIdx.x] && a2 < sarg[threadIdx.x])) {
                        smin[threadIdx.x] = s2; sarg[threadIdx.x] = a2;
                    }
                }
                __syncthreads();
            }
            float dmin = smin[0]; int arg = sarg[0];
            if (dmin < THRESHV) {
                const float* rec = mem2 + (size_t)mapping[arg] * DD;
                for (int d = threadIdx.x; d < DD; d += blockDim.x) {
                    int c = d >> 10, rem = d & 1023, ky = rem >> 5, kx = rem & 31;
                    int y = y0 + ky, x = x0 + kx;
                    if (y >= 0 && y < HH && x >= 0 && x < WW) {
                        float u = img[((size_t)y * WW + x) * CC + c];
                        atomicAdd(&out[((size_t)y * WW + x) * CC + c],
                                  rec[d] - u);
                    }
                }
            }
            __syncthreads();
        }
    }
}

// Kernel D: if any patch was uncertified, recompute per-block maxes of the
// (possibly patched) output into pmaxB. Normally: read 126 counts, exit.
__global__ void rescan_max(const uint32_t* __restrict__ counts,
                           const float* __restrict__ out,
                           float* __restrict__ pmaxB) {
    __shared__ int sneed[4];
    __shared__ float smx[4];
    int tid = threadIdx.x, lane = tid & 63, w = tid >> 6;
    int c = (tid < NPATCH) ? (int)counts[tid] : 0;
    c = wave_sum_i(c);
    if (lane == 0) sneed[w] = c;
    __syncthreads();
    int need = sneed[0] + sneed[1] + sneed[2] + sneed[3];
    if (need == 0) return;
    float m = -INFINITY;
    if (tid < 192) {
        int f = blockIdx.x * 192 + tid;
        float4 v = ((const float4*)out)[f];
        m = fmaxf(fmaxf(v.x, v.y), fmaxf(v.z, v.w));
    }
    m = wave_max(m);
    if (lane == 0) smx[w] = m;
    __syncthreads();
    if (tid == 0)
        pmaxB[blockIdx.x] = fmaxf(fmaxf(smx[0], smx[1]), fmaxf(smx[2], smx[3]));
}

// Kernel E: reduce the 1024 partial maxes (choosing A or B by fail counts),
// then divide the output by the global max. 256 blocks x 256 threads x 3 f4.
__global__ void normalize_k(const uint32_t* __restrict__ counts,
                            const float* __restrict__ pmaxA,
                            const float* __restrict__ pmaxB,
                            float* __restrict__ out) {
    __shared__ int sneed[4];
    __shared__ float smx[4];
    __shared__ float s_inv;
    int tid = threadIdx.x, lane = tid & 63, w = tid >> 6;
    int c = (tid < NPATCH) ? (int)counts[tid] : 0;
    c = wave_sum_i(c);
    if (lane == 0) sneed[w] = c;
    __syncthreads();
    int need = sneed[0] + sneed[1] + sneed[2] + sneed[3];
    const float* pm = need ? pmaxB : pmaxA;
    float m = -INFINITY;
#pragma unroll
    for (int k = 0; k < 4; ++k) m = fmaxf(m, pm[tid + (k << 8)]);
    m = wave_max(m);
    if (lane == 0) smx[w] = m;
    __syncthreads();
    if (tid == 0)
        s_inv = 1.0f / fmaxf(fmaxf(smx[0], smx[1]), fmaxf(smx[2], smx[3]));
    __syncthreads();
    float inv = s_inv;
    float4* o4 = (float4*)out;
    int base = blockIdx.x * 768 + tid;
#pragma unroll
    for (int k = 0; k < 3; ++k) {
        int f = base + (k << 8);
        float4 v = o4[f];
        v.x *= inv; v.y *= inv; v.z *= inv; v.w *= inv;
        o4[f] = v;
    }
}

extern "C" void kernel_launch(void* const* d_in, const int* in_sizes, int n_in,
                              void* d_out, int out_size, void* d_ws, size_t ws_size,
                              hipStream_t stream) {
    const float* img     = (const float*)d_in[0];
    const float* mem     = (const float*)d_in[1];
    const float* mem2    = (const float*)d_in[2];
    const int*   mapping = (const int*)d_in[3];
    float* out    = (float*)d_out;
    uint32_t* wsu = (uint32_t*)d_ws;

    float*    norms  = (float*)(wsu + OFF_NORMS);
    uint32_t* counts = wsu + OFF_CNT;
    uint32_t* fails  = wsu + OFF_FAIL;
    float*    pmaxA  = (float*)(wsu + OFF_PMAXA);
    float*    pmaxB  = (float*)(wsu + OFF_PMAXB);

    norms_fold <<<1024, 256, 0, stream>>>(mem, img, norms, pmaxA, out);
    patch_cert <<<NPATCH, 512, 0, stream>>>(img, norms, counts, fails);
    fallback_fix<<<64, 256, 0, stream>>>(img, mem, mem2, mapping, counts,
                                         fails, out);
    rescan_max <<<1024, 256, 0, stream>>>(counts, out, pmaxB);
    normalize_k<<<256, 256, 0, stream>>>(counts, pmaxA, pmaxB, out);
}